// Round 2
// baseline (453.657 us; speedup 1.0000x reference)
//
#include <hip/hip_runtime.h>
#include <hip/hip_bf16.h>
#include <math.h>

#define N_NODES 40000
#define N_EDGES 1280000
#define D_FEAT 1024
#define HIDDEN 64
#define N_CLASSES 40
#define NB 157            // scan blocks of 256 nodes: ceil(40000/256)

typedef _Float16 f16x8 __attribute__((ext_vector_type(8)));
typedef float f32x4 __attribute__((ext_vector_type(4)));

// ---------------- pass 0: node-degree histogram (global atomics) + W1 transpose ----------------
// grid = 1250 edge blocks (1024 edges each, int4 loads) + 256 Wt blocks

#define EDGE_BLOCKS 1250

__global__ __launch_bounds__(256) void k_preA(const int* __restrict__ col,
                                              int* __restrict__ deg,
                                              const float* __restrict__ W,
                                              _Float16* __restrict__ Wt) {
    const int tid = threadIdx.x;
    if (blockIdx.x < EDGE_BLOCKS) {
        int e0 = blockIdx.x * 1024 + tid * 4;          // 1250*1024 == N_EDGES exactly
        int4 c = *(const int4*)&col[e0];
        atomicAdd(&deg[c.x], 1);
        atomicAdd(&deg[c.y], 1);
        atomicAdd(&deg[c.z], 1);
        atomicAdd(&deg[c.w], 1);
    } else {
        int i = (blockIdx.x - EDGE_BLOCKS) * 256 + tid;
        int n = i & 63, k = i >> 6;
        Wt[n * D_FEAT + k] = (_Float16)W[k * HIDDEN + n];
    }
}

// ---------------- scan: deg -> off (exclusive), pos=off, dinv ----------------

__global__ __launch_bounds__(256) void k_scanA(const int* __restrict__ deg,
                                               int* __restrict__ lsum,
                                               int* __restrict__ bsum) {
    __shared__ int sc[256];
    const int tid = threadIdx.x;
    const int i = blockIdx.x * 256 + tid;
    int v = (i < N_NODES) ? deg[i] : 0;
    sc[tid] = v;
    __syncthreads();
#pragma unroll
    for (int d = 1; d < 256; d <<= 1) {
        int t = (tid >= d) ? sc[tid - d] : 0;
        __syncthreads();
        sc[tid] += t;
        __syncthreads();
    }
    if (i < N_NODES) lsum[i] = sc[tid] - v;   // block-local exclusive
    if (tid == 255) bsum[blockIdx.x] = sc[255];
}

__global__ __launch_bounds__(256) void k_scanB(const int* __restrict__ bsum,
                                               int* __restrict__ bbase) {
    __shared__ int sc[256];
    const int tid = threadIdx.x;
    int v = (tid < NB) ? bsum[tid] : 0;
    sc[tid] = v;
    __syncthreads();
#pragma unroll
    for (int d = 1; d < 256; d <<= 1) {
        int t = (tid >= d) ? sc[tid - d] : 0;
        __syncthreads();
        sc[tid] += t;
        __syncthreads();
    }
    if (tid < NB) bbase[tid] = sc[tid] - v;   // exclusive block base
}

__global__ __launch_bounds__(256) void k_scanC(const int* __restrict__ deg,
                                               const int* __restrict__ lsum,
                                               const int* __restrict__ bbase,
                                               int* __restrict__ off,
                                               int* __restrict__ pos,
                                               float* __restrict__ dinv) {
    const int i = blockIdx.x * 256 + threadIdx.x;
    if (i < N_NODES) {
        int v = lsum[i] + bbase[blockIdx.x];
        off[i] = v;
        pos[i] = v;
        dinv[i] = rsqrtf((float)(deg[i] + 1));   // +1 self-loop
    }
    if (i == 0) off[N_NODES] = N_EDGES;
}

// ---------------- scatter: CSR fill. sorted[pos[col]++] = row ----------------

__global__ __launch_bounds__(256) void k_scatter(const int* __restrict__ row,
                                                 const int* __restrict__ col,
                                                 int* __restrict__ pos,
                                                 unsigned short* __restrict__ sorted) {
    int e0 = blockIdx.x * 1024 + threadIdx.x * 4;   // grid = 1250, exact cover
    int4 c = *(const int4*)&col[e0];
    int4 r = *(const int4*)&row[e0];
    int p0 = atomicAdd(&pos[c.x], 1); sorted[p0] = (unsigned short)r.x;
    int p1 = atomicAdd(&pos[c.y], 1); sorted[p1] = (unsigned short)r.y;
    int p2 = atomicAdd(&pos[c.z], 1); sorted[p2] = (unsigned short)r.z;
    int p3 = atomicAdd(&pos[c.w], 1); sorted[p3] = (unsigned short)r.w;
}

// ---------------- GEMM1 (f16 MFMA): hs1[i,j] = f16((x[i,:] @ W1[:,j]) * dinv[i]) ----------------
// 32x64 tile per 256-thread block (1250 blocks), BK=64, packed f16x8 staging.
// X loads nontemporal: zero-reuse stream, keep it out of L2/L3.

#define LDA 72
#define LDB 72

__global__ __launch_bounds__(256) void k_gemm1(const float* __restrict__ X,
                                               const _Float16* __restrict__ Wt,
                                               const float* __restrict__ dinv,
                                               _Float16* __restrict__ out) {
    __shared__ _Float16 As[32 * LDA];
    __shared__ _Float16 Bs[64 * LDB];
    const int tid = threadIdx.x;
    const int wave = tid >> 6, lane = tid & 63;
    const int row0 = blockIdx.x * 32;
    const int m0 = (wave & 1) * 16, n0 = (wave >> 1) * 32;
    const int lr = lane & 15, quad = lane >> 4;

    const int ar = tid >> 3;          // 0..31 A row
    const int ak = (tid & 7) * 8;     // K offset (8 floats)
    const int bn = tid >> 2;          // 0..63 B row (n)
    const int bk = (tid & 3) * 16;    // K offset (16 halves)

    f32x4 acc0 = {0.f,0.f,0.f,0.f}, acc1 = {0.f,0.f,0.f,0.f};

    for (int k0 = 0; k0 < D_FEAT; k0 += 64) {
        const f32x4* xp = (const f32x4*)&X[(row0 + ar) * D_FEAT + k0 + ak];
        f32x4 v0 = __builtin_nontemporal_load(xp);
        f32x4 v1 = __builtin_nontemporal_load(xp + 1);
        f16x8 p0 = {(_Float16)v0[0],(_Float16)v0[1],(_Float16)v0[2],(_Float16)v0[3],
                    (_Float16)v1[0],(_Float16)v1[1],(_Float16)v1[2],(_Float16)v1[3]};
        *(f16x8*)&As[ar * LDA + ak] = p0;
        const uint4* wp = (const uint4*)&Wt[bn * D_FEAT + k0 + bk];
        uint4 w0 = wp[0], w1 = wp[1];
        *(uint4*)&Bs[bn * LDB + bk]     = w0;
        *(uint4*)&Bs[bn * LDB + bk + 8] = w1;
        __syncthreads();
#pragma unroll
        for (int kk = 0; kk < 64; kk += 32) {
            f16x8 a  = *(f16x8*)&As[(m0 + lr) * LDA + kk + quad * 8];
            f16x8 b0 = *(f16x8*)&Bs[(n0 + lr) * LDB + kk + quad * 8];
            f16x8 b1 = *(f16x8*)&Bs[(n0 + 16 + lr) * LDB + kk + quad * 8];
            acc0 = __builtin_amdgcn_mfma_f32_16x16x32_f16(a, b0, acc0, 0, 0, 0);
            acc1 = __builtin_amdgcn_mfma_f32_16x16x32_f16(a, b1, acc1, 0, 0, 0);
        }
        __syncthreads();
    }

#pragma unroll
    for (int r = 0; r < 4; ++r) {
        int m = row0 + m0 + quad * 4 + r;
        float dv = dinv[m];
        out[m * HIDDEN + n0 + lr]      = (_Float16)(acc0[r] * dv);
        out[m * HIDDEN + n0 + 16 + lr] = (_Float16)(acc1[r] * dv);
    }
}

// ---------------- gather1: A1[node] = f16( dinv * relu(dinv * agg(B1) + b1) ) ----------------
// wave per node; wave = 8 edge-groups x 8 feature-slices. One dwordx4 load covers
// 16 B (8 f16 features) of one edge row -> 8 edges per load instruction.
// Pairwise f16 pre-add (v_pk_add_f16) halves the f32 accumulate work.

__global__ __launch_bounds__(256) void k_agg1(const int* __restrict__ off,
                                              const unsigned short* __restrict__ sorted,
                                              const _Float16* __restrict__ hs,
                                              const float* __restrict__ dinv,
                                              const float* __restrict__ bias,
                                              _Float16* __restrict__ A1) {
    const int tid = threadIdx.x;
    const int wave = tid >> 6, lane = tid & 63;
    const int node = blockIdx.x * 4 + wave;
    const int g = lane >> 3;      // edge slot within a 16-edge step
    const int sl = lane & 7;      // feature slice (8 f16 = 16 B)

    float acc[8];
#pragma unroll
    for (int j = 0; j < 8; ++j) acc[j] = 0.f;
    if (g == 0) {                 // self-loop counted exactly once (group 0)
        f16x8 v = *(const f16x8*)&hs[node * HIDDEN + sl * 8];
#pragma unroll
        for (int j = 0; j < 8; ++j) acc[j] = (float)v[j];
    }

    const int beg = off[node], end = off[node + 1];
    for (int base = beg; base < end; base += 64) {
        int m = end - base; if (m > 64) m = 64;
        int vidx = (lane < m) ? (int)sorted[base + lane] : 0;
        int nfull = m & ~15;
        int i = 0;
        for (; i < nfull; i += 16) {          // 16 edges, 2 loads/lane in flight
            int s0 = __shfl(vidx, i + g, 64);
            int s1 = __shfl(vidx, i + 8 + g, 64);
            f16x8 v0 = *(const f16x8*)&hs[s0 * HIDDEN + sl * 8];
            f16x8 v1 = *(const f16x8*)&hs[s1 * HIDDEN + sl * 8];
            f16x8 t = v0 + v1;                // v_pk_add_f16 x4
#pragma unroll
            for (int j = 0; j < 8; ++j)
                acc[j] += (float)t[j];
        }
        if (i < m) {                          // masked tail (<16 edges)
            int s0 = __shfl(vidx, i + g, 64);
            int s1 = __shfl(vidx, i + 8 + g, 64);   // i+8+g <= 63 always
            f16x8 v0 = {};
            f16x8 v1 = {};
            if (i + g < m)     v0 = *(const f16x8*)&hs[s0 * HIDDEN + sl * 8];
            if (i + 8 + g < m) v1 = *(const f16x8*)&hs[s1 * HIDDEN + sl * 8];
            f16x8 t = v0 + v1;
#pragma unroll
            for (int j = 0; j < 8; ++j)
                acc[j] += (float)t[j];
        }
    }

    // fold the 8 edge-groups (bits 3..5 of lane)
#pragma unroll
    for (int j = 0; j < 8; ++j) {
        acc[j] += __shfl_xor(acc[j], 8, 64);
        acc[j] += __shfl_xor(acc[j], 16, 64);
        acc[j] += __shfl_xor(acc[j], 32, 64);
    }
    if (lane < 8) {
        float dv = dinv[node];
        f16x8 o;
#pragma unroll
        for (int j = 0; j < 8; ++j) {
            float z = fmaf(dv, acc[j], bias[lane * 8 + j]);
            o[j] = (_Float16)(fmaxf(z, 0.f) * dv);   // pre-scale for layer-2 source norm
        }
        *(f16x8*)&A1[node * HIDDEN + lane * 8] = o;
    }
}

// ---------------- gather2 + GEMV(64x40) + log-softmax ----------------
// linearity: Agg(norm * (a1 @ W2)) == Agg(norm * a1) @ W2 -> aggregate in 64-dim,
// then one GEMV per node. Same 8x8 gather structure as k_agg1.

__global__ __launch_bounds__(256) void k_agg2_lsm(const int* __restrict__ off,
                                                  const unsigned short* __restrict__ sorted,
                                                  const _Float16* __restrict__ A1,
                                                  const float* __restrict__ dinv,
                                                  const float* __restrict__ b2,
                                                  const float* __restrict__ W2,
                                                  float* __restrict__ out) {
    __shared__ float W2s[HIDDEN * N_CLASSES];   // [k][c], as given
    __shared__ float aggs[4][HIDDEN];
    const int tid = threadIdx.x;
    for (int i = tid; i < HIDDEN * N_CLASSES; i += 256) W2s[i] = W2[i];
    const int wave = tid >> 6, lane = tid & 63;
    const int node = blockIdx.x * 4 + wave;
    const int g = lane >> 3, sl = lane & 7;

    float acc[8];
#pragma unroll
    for (int j = 0; j < 8; ++j) acc[j] = 0.f;
    if (g == 0) {
        f16x8 v = *(const f16x8*)&A1[node * HIDDEN + sl * 8];
#pragma unroll
        for (int j = 0; j < 8; ++j) acc[j] = (float)v[j];
    }
    __syncthreads();   // W2s staged; placed before divergent-length gather

    const int beg = off[node], end = off[node + 1];
    for (int base = beg; base < end; base += 64) {
        int m = end - base; if (m > 64) m = 64;
        int vidx = (lane < m) ? (int)sorted[base + lane] : 0;
        int nfull = m & ~15;
        int i = 0;
        for (; i < nfull; i += 16) {
            int s0 = __shfl(vidx, i + g, 64);
            int s1 = __shfl(vidx, i + 8 + g, 64);
            f16x8 v0 = *(const f16x8*)&A1[s0 * HIDDEN + sl * 8];
            f16x8 v1 = *(const f16x8*)&A1[s1 * HIDDEN + sl * 8];
            f16x8 t = v0 + v1;
#pragma unroll
            for (int j = 0; j < 8; ++j)
                acc[j] += (float)t[j];
        }
        if (i < m) {
            int s0 = __shfl(vidx, i + g, 64);
            int s1 = __shfl(vidx, i + 8 + g, 64);
            f16x8 v0 = {};
            f16x8 v1 = {};
            if (i + g < m)     v0 = *(const f16x8*)&A1[s0 * HIDDEN + sl * 8];
            if (i + 8 + g < m) v1 = *(const f16x8*)&A1[s1 * HIDDEN + sl * 8];
            f16x8 t = v0 + v1;
#pragma unroll
            for (int j = 0; j < 8; ++j)
                acc[j] += (float)t[j];
        }
    }
#pragma unroll
    for (int j = 0; j < 8; ++j) {
        acc[j] += __shfl_xor(acc[j], 8, 64);
        acc[j] += __shfl_xor(acc[j], 16, 64);
        acc[j] += __shfl_xor(acc[j], 32, 64);
    }
    if (lane < 8) {
        f32x4 t0 = {acc[0], acc[1], acc[2], acc[3]};
        f32x4 t1 = {acc[4], acc[5], acc[6], acc[7]};
        *(f32x4*)&aggs[wave][lane * 8]     = t0;
        *(f32x4*)&aggs[wave][lane * 8 + 4] = t1;
    }
    __builtin_amdgcn_wave_barrier();   // same-wave LDS write->read ordering fence

    float z = -INFINITY;
    if (lane < N_CLASSES) {
        float s = 0.f;
        const float* ag = aggs[wave];
#pragma unroll
        for (int k = 0; k < HIDDEN; ++k)
            s = fmaf(ag[k], W2s[k * N_CLASSES + lane], s);
        z = fmaf(dinv[node], s, b2[lane]);
    }
    float mv = z;
#pragma unroll
    for (int d = 32; d > 0; d >>= 1) mv = fmaxf(mv, __shfl_xor(mv, d, 64));
    float ex = (lane < N_CLASSES) ? expf(z - mv) : 0.f;
#pragma unroll
    for (int d = 32; d > 0; d >>= 1) ex += __shfl_xor(ex, d, 64);
    float lse = mv + logf(ex);
    if (lane < N_CLASSES) out[node * N_CLASSES + lane] = z - lse;
}

// ---------------- launch ----------------

extern "C" void kernel_launch(void* const* d_in, const int* in_sizes, int n_in,
                              void* d_out, int out_size, void* d_ws, size_t ws_size,
                              hipStream_t stream) {
    const float* x  = (const float*)d_in[0];
    const int*   ei = (const int*)d_in[1];
    const float* W1 = (const float*)d_in[2];
    const float* b1 = (const float*)d_in[3];
    const float* W2 = (const float*)d_in[4];
    const float* b2 = (const float*)d_in[5];
    const int* row = ei;             // edge_index[0] = source
    const int* col = ei + N_EDGES;   // edge_index[1] = target

    char* ws = (char*)d_ws;
    int*            deg    = (int*)(ws + 0);             // 160 KB
    int*            lsum   = (int*)(ws + 163840);        // 160 KB
    int*            bsum   = (int*)(ws + 327680);        // 628 B
    int*            bbase  = (int*)(ws + 331776);        // 628 B
    int*            off    = (int*)(ws + 335872);        // 160 KB + 4
    int*            pos    = (int*)(ws + 499712);        // 160 KB
    float*          dinv   = (float*)(ws + 663552);      // 160 KB
    unsigned short* sorted = (unsigned short*)(ws + 827392);  // 2.56 MB
    _Float16*       W1t    = (_Float16*)(ws + 3387392);  // 128 KB
    _Float16*       B1     = (_Float16*)(ws + 3518464);  // 5.12 MB : hs1 f16
    _Float16*       A1     = (_Float16*)(ws + 8638464);  // 5.12 MB

    hipMemsetAsync(deg, 0, N_NODES * sizeof(int), stream);
    k_preA<<<EDGE_BLOCKS + 256, 256, 0, stream>>>(col, deg, W1, W1t);
    k_scanA<<<NB, 256, 0, stream>>>(deg, lsum, bsum);
    k_scanB<<<1, 256, 0, stream>>>(bsum, bbase);
    k_scanC<<<NB, 256, 0, stream>>>(deg, lsum, bbase, off, pos, dinv);
    k_scatter<<<EDGE_BLOCKS, 256, 0, stream>>>(row, col, pos, sorted);

    k_gemm1<<<N_NODES / 32, 256, 0, stream>>>(x, W1t, dinv, B1);
    k_agg1<<<N_NODES / 4, 256, 0, stream>>>(off, sorted, B1, dinv, b1, A1);
    k_agg2_lsm<<<N_NODES / 4, 256, 0, stream>>>(off, sorted, A1, dinv, b2, W2, (float*)d_out);
}

// Round 3
// 382.861 us; speedup vs baseline: 1.1849x; 1.1849x over previous
//
#include <hip/hip_runtime.h>
#include <hip/hip_bf16.h>
#include <math.h>

#define N_NODES 40000
#define N_EDGES 1280000
#define D_FEAT 1024
#define HIDDEN 64
#define N_CLASSES 40
#define NB 157            // buckets of 256 destination cols: ceil(40000/256)
#define CHUNK 4096        // edges per k_binscatter block (16 per thread)

typedef _Float16 f16x8 __attribute__((ext_vector_type(8)));
typedef float f32x4 __attribute__((ext_vector_type(4)));

// ---------------- fused pass 0: bucket histogram + W1 transpose/convert ----------------

#define HIST_BLOCKS 313   // ceil(1280000/4096)
#define CONV_BLOCKS 256   // 65536/256

__global__ __launch_bounds__(256) void k_pre(const int* __restrict__ col,
                                             int* __restrict__ btot,
                                             const float* __restrict__ W,
                                             _Float16* __restrict__ Wt) {
    __shared__ int h[NB];
    int tid = threadIdx.x;
    if (blockIdx.x < HIST_BLOCKS) {
        if (tid < NB) h[tid] = 0;
        __syncthreads();
        int e0 = blockIdx.x * 4096;
        int e1 = min(e0 + 4096, N_EDGES);
        for (int e = e0 + tid; e < e1; e += 256)
            atomicAdd(&h[col[e] >> 8], 1);
        __syncthreads();
        if (tid < NB && h[tid]) atomicAdd(&btot[tid], h[tid]);
    } else {
        int i = (blockIdx.x - HIST_BLOCKS) * 256 + tid;
        int n = i & 63, k = i >> 6;
        Wt[n * D_FEAT + k] = (_Float16)W[k * HIDDEN + n];
    }
}

// ---------------- pass 1: bin edges, bucket-ordered in LDS, coalesced flush ----------------
// sedge element: (col&255)<<16 | row   (row < 40000 < 2^16)

__global__ __launch_bounds__(256) void k_binscatter(const int* __restrict__ row,
                                                    const int* __restrict__ col,
                                                    const int* __restrict__ btot,
                                                    int* __restrict__ gcur,
                                                    unsigned* __restrict__ sedge) {
    __shared__ unsigned stage[CHUNK];
    __shared__ unsigned char bo[CHUNK];
    __shared__ int sc[256];
    __shared__ int bb[NB];
    __shared__ int hist[NB];
    __shared__ int lo[NB];
    __shared__ int cur[NB];
    __shared__ int dst[NB];
    const int tid = threadIdx.x;
    const int e0 = blockIdx.x * CHUNK;
    const int nE = min(CHUNK, N_EDGES - e0);

    if (tid < NB) { hist[tid] = 0; cur[tid] = 0; }
    int bv = (tid < NB) ? btot[tid] : 0;
    sc[tid] = bv;
    __syncthreads();
#pragma unroll
    for (int d = 1; d < 256; d <<= 1) {
        int t = (tid >= d) ? sc[tid - d] : 0;
        __syncthreads();
        sc[tid] += t;
        __syncthreads();
    }
    if (tid < NB) bb[tid] = sc[tid] - bv;   // exclusive bucket base (global)

    int c[16];
#pragma unroll
    for (int t = 0; t < 16; ++t) {
        int e = tid + t * 256;
        c[t] = (e < nE) ? col[e0 + e] : -1;
        if (e < nE) atomicAdd(&hist[c[t] >> 8], 1);
    }
    __syncthreads();

    int hv = (tid < NB) ? hist[tid] : 0;
    sc[tid] = hv;
    __syncthreads();
#pragma unroll
    for (int d = 1; d < 256; d <<= 1) {
        int t = (tid >= d) ? sc[tid - d] : 0;
        __syncthreads();
        sc[tid] += t;
        __syncthreads();
    }
    if (tid < NB) {
        int excl = sc[tid] - hv;
        lo[tid] = excl;
        int cp = hv ? atomicAdd(&gcur[tid], hv) : 0;
        dst[tid] = bb[tid] + cp - excl;     // global addr = dst[b] + ldsIdx
    }
    __syncthreads();

#pragma unroll
    for (int t = 0; t < 16; ++t) {
        int e = tid + t * 256;
        if (e < nE) {
            int b = c[t] >> 8;
            int p = lo[b] + atomicAdd(&cur[b], 1);
            stage[p] = ((unsigned)(c[t] & 255) << 16) | (unsigned)row[e0 + e];
            bo[p] = (unsigned char)b;
        }
    }
    __syncthreads();
    for (int i = tid; i < nE; i += 256)
        sedge[dst[bo[i]] + i] = stage[i];   // coalesced: consecutive i -> consecutive addr per run
}

// ---------------- pass 2: per-bucket counting sort; emits off[], dinv[], sorted[] (u16) ----------------

__global__ __launch_bounds__(256) void k_bucketsort(const unsigned* __restrict__ sedge,
                                                    const int* __restrict__ btot,
                                                    int* __restrict__ off,
                                                    float* __restrict__ dinv,
                                                    unsigned short* __restrict__ sorted) {
    __shared__ int sc[256];
    __shared__ int hist[256];
    __shared__ int cur[256];
    const int tid = threadIdx.x;
    const int b = blockIdx.x;
    int bv = (tid < NB) ? btot[tid] : 0;
    sc[tid] = bv;
    hist[tid] = 0;
    __syncthreads();
#pragma unroll
    for (int d = 1; d < 256; d <<= 1) {
        int t = (tid >= d) ? sc[tid - d] : 0;
        __syncthreads();
        sc[tid] += t;
        __syncthreads();
    }
    const int base = (b == 0) ? 0 : sc[b - 1];
    const int end  = sc[b];
    __syncthreads();

    for (int i = base + tid; i < end; i += 256)
        atomicAdd(&hist[sedge[i] >> 16], 1);
    __syncthreads();
    int v = hist[tid];
    sc[tid] = v;
    __syncthreads();
#pragma unroll
    for (int d = 1; d < 256; d <<= 1) {
        int t = (tid >= d) ? sc[tid - d] : 0;
        __syncthreads();
        sc[tid] += t;
        __syncthreads();
    }
    int excl = sc[tid] - v;
    cur[tid] = excl;
    int col0 = b << 8;
    int ncol = min(256, N_NODES - col0);
    if (tid < ncol) {
        off[col0 + tid] = base + excl;
        dinv[col0 + tid] = rsqrtf((float)(v + 1));   // +1 self-loop
    }
    if (b == NB - 1 && tid == 0) off[N_NODES] = N_EDGES;
    __syncthreads();
    for (int i = base + tid; i < end; i += 256) {
        unsigned e = sedge[i];
        int p = atomicAdd(&cur[e >> 16], 1);
        sorted[base + p] = (unsigned short)e;
    }
}

// ---------------- GEMM1 v2 (f16 MFMA): 64x64 tile, double-buffered LDS, reg prefetch ----------
// hs1[i,j] = f16((x[i,:] @ W1[:,j]) * dinv[i]); 625 blocks, 1 barrier per K-iter.

#define LDA 72
#define LDB 72

__global__ __launch_bounds__(256) void k_gemm1(const float* __restrict__ X,
                                               const _Float16* __restrict__ Wt,
                                               const float* __restrict__ dinv,
                                               _Float16* __restrict__ out) {
    __shared__ _Float16 As[2][64 * LDA];
    __shared__ _Float16 Bs[2][64 * LDB];
    const int tid = threadIdx.x;
    const int wave = tid >> 6, lane = tid & 63;
    const int row0 = blockIdx.x * 64;
    const int m0 = (wave & 1) * 32, n0 = (wave >> 1) * 32;
    const int lr = lane & 15, quad = lane >> 4;

    const int ar = tid >> 2;          // 0..63 A row
    const int ak = (tid & 3) * 16;    // K offset (16 floats, 64 B contiguous)
    const int bn = tid >> 2;          // 0..63 B row (n)
    const int bk = (tid & 3) * 16;    // K offset (16 halves)

    f32x4 acc00 = {0.f,0.f,0.f,0.f}, acc01 = {0.f,0.f,0.f,0.f};
    f32x4 acc10 = {0.f,0.f,0.f,0.f}, acc11 = {0.f,0.f,0.f,0.f};

    float4 xv0, xv1, xv2, xv3;
    uint4 wv0, wv1;

#define GLOAD(K0) {                                                          \
        const float4* xp = (const float4*)&X[(row0 + ar) * D_FEAT + (K0) + ak]; \
        xv0 = xp[0]; xv1 = xp[1]; xv2 = xp[2]; xv3 = xp[3];                  \
        const uint4* wp = (const uint4*)&Wt[bn * D_FEAT + (K0) + bk];        \
        wv0 = wp[0]; wv1 = wp[1]; }

#define LSTORE(B) {                                                          \
        f16x8 p0 = {(_Float16)xv0.x,(_Float16)xv0.y,(_Float16)xv0.z,(_Float16)xv0.w, \
                    (_Float16)xv1.x,(_Float16)xv1.y,(_Float16)xv1.z,(_Float16)xv1.w}; \
        f16x8 p1 = {(_Float16)xv2.x,(_Float16)xv2.y,(_Float16)xv2.z,(_Float16)xv2.w, \
                    (_Float16)xv3.x,(_Float16)xv3.y,(_Float16)xv3.z,(_Float16)xv3.w}; \
        *(f16x8*)&As[B][ar * LDA + ak]     = p0;                             \
        *(f16x8*)&As[B][ar * LDA + ak + 8] = p1;                             \
        *(uint4*)&Bs[B][bn * LDB + bk]     = wv0;                            \
        *(uint4*)&Bs[B][bn * LDB + bk + 8] = wv1; }

#define MFMA_STEP(B) {                                                       \
        _Pragma("unroll")                                                    \
        for (int kk = 0; kk < 64; kk += 32) {                                \
            f16x8 a0 = *(f16x8*)&As[B][(m0 + lr) * LDA + kk + quad * 8];     \
            f16x8 a1 = *(f16x8*)&As[B][(m0 + 16 + lr) * LDA + kk + quad * 8];\
            f16x8 b0 = *(f16x8*)&Bs[B][(n0 + lr) * LDB + kk + quad * 8];     \
            f16x8 b1 = *(f16x8*)&Bs[B][(n0 + 16 + lr) * LDB + kk + quad * 8];\
            acc00 = __builtin_amdgcn_mfma_f32_16x16x32_f16(a0, b0, acc00, 0, 0, 0); \
            acc01 = __builtin_amdgcn_mfma_f32_16x16x32_f16(a0, b1, acc01, 0, 0, 0); \
            acc10 = __builtin_amdgcn_mfma_f32_16x16x32_f16(a1, b0, acc10, 0, 0, 0); \
            acc11 = __builtin_amdgcn_mfma_f32_16x16x32_f16(a1, b1, acc11, 0, 0, 0); \
        } }

    GLOAD(0);
    LSTORE(0);
    __syncthreads();
    int buf = 0;
    for (int k0 = 64; k0 < D_FEAT; k0 += 64) {
        GLOAD(k0);              // issue next-tile loads early (hide under MFMA)
        MFMA_STEP(buf);
        LSTORE(buf ^ 1);        // waits on loads, writes other buffer
        __syncthreads();
        buf ^= 1;
    }
    MFMA_STEP(buf);

#pragma unroll
    for (int r = 0; r < 4; ++r) {
        int m = row0 + m0 + quad * 4 + r;
        float dv0 = dinv[m], dv1 = dinv[m + 16];
        out[m * HIDDEN + n0 + lr]             = (_Float16)(acc00[r] * dv0);
        out[m * HIDDEN + n0 + 16 + lr]        = (_Float16)(acc01[r] * dv0);
        out[(m + 16) * HIDDEN + n0 + lr]      = (_Float16)(acc10[r] * dv1);
        out[(m + 16) * HIDDEN + n0 + 16 + lr] = (_Float16)(acc11[r] * dv1);
    }
#undef GLOAD
#undef LSTORE
#undef MFMA_STEP
}

// ---------------- gather1: A1[node] = f16( dinv * relu(dinv * agg(B1) + b1) ) ----------------
// wave per node; wave = 8 edge-groups x 8 feature-slices. One dwordx4 load covers
// 16 B (8 f16 features) of one edge row -> 8 edges per load instruction.

__global__ __launch_bounds__(256) void k_agg1(const int* __restrict__ off,
                                              const unsigned short* __restrict__ sorted,
                                              const _Float16* __restrict__ hs,
                                              const float* __restrict__ dinv,
                                              const float* __restrict__ bias,
                                              _Float16* __restrict__ A1) {
    const int tid = threadIdx.x;
    const int wave = tid >> 6, lane = tid & 63;
    const int node = blockIdx.x * 4 + wave;
    const int g = lane >> 3;      // edge slot within a 16-edge step
    const int sl = lane & 7;      // feature slice (8 f16 = 16 B)

    float acc[8];
#pragma unroll
    for (int j = 0; j < 8; ++j) acc[j] = 0.f;
    if (g == 0) {                 // self-loop counted exactly once (group 0)
        f16x8 v = *(const f16x8*)&hs[node * HIDDEN + sl * 8];
#pragma unroll
        for (int j = 0; j < 8; ++j) acc[j] = (float)v[j];
    }

    const int beg = off[node], end = off[node + 1];
    for (int base = beg; base < end; base += 64) {
        int m = end - base; if (m > 64) m = 64;
        int vidx = (lane < m) ? (int)sorted[base + lane] : 0;
        int nfull = m & ~15;
        int i = 0;
        for (; i < nfull; i += 16) {          // 16 edges, 2 loads/lane in flight
            int s0 = __shfl(vidx, i + g, 64);
            int s1 = __shfl(vidx, i + 8 + g, 64);
            f16x8 v0 = *(const f16x8*)&hs[s0 * HIDDEN + sl * 8];
            f16x8 v1 = *(const f16x8*)&hs[s1 * HIDDEN + sl * 8];
            f16x8 t = v0 + v1;                // v_pk_add_f16 x4
#pragma unroll
            for (int j = 0; j < 8; ++j)
                acc[j] += (float)t[j];
        }
        if (i < m) {                          // masked tail (<16 edges)
            int s0 = __shfl(vidx, i + g, 64);
            int s1 = __shfl(vidx, i + 8 + g, 64);   // i+8+g <= 63 always
            f16x8 v0 = {};
            f16x8 v1 = {};
            if (i + g < m)     v0 = *(const f16x8*)&hs[s0 * HIDDEN + sl * 8];
            if (i + 8 + g < m) v1 = *(const f16x8*)&hs[s1 * HIDDEN + sl * 8];
            f16x8 t = v0 + v1;
#pragma unroll
            for (int j = 0; j < 8; ++j)
                acc[j] += (float)t[j];
        }
    }

    // fold the 8 edge-groups (bits 3..5 of lane)
#pragma unroll
    for (int j = 0; j < 8; ++j) {
        acc[j] += __shfl_xor(acc[j], 8, 64);
        acc[j] += __shfl_xor(acc[j], 16, 64);
        acc[j] += __shfl_xor(acc[j], 32, 64);
    }
    if (lane < 8) {
        float dv = dinv[node];
        f16x8 o;
#pragma unroll
        for (int j = 0; j < 8; ++j) {
            float z = fmaf(dv, acc[j], bias[lane * 8 + j]);
            o[j] = (_Float16)(fmaxf(z, 0.f) * dv);   // pre-scale for layer-2 source norm
        }
        *(f16x8*)&A1[node * HIDDEN + lane * 8] = o;
    }
}

// ---------------- gather2 + GEMV(64x40) + log-softmax ----------------
// linearity: Agg(norm * (a1 @ W2)) == Agg(norm * a1) @ W2 -> aggregate in 64-dim,
// then one GEMV per node. Same 8x8 gather structure as k_agg1.

__global__ __launch_bounds__(256) void k_agg2_lsm(const int* __restrict__ off,
                                                  const unsigned short* __restrict__ sorted,
                                                  const _Float16* __restrict__ A1,
                                                  const float* __restrict__ dinv,
                                                  const float* __restrict__ b2,
                                                  const float* __restrict__ W2,
                                                  float* __restrict__ out) {
    __shared__ float W2s[HIDDEN * N_CLASSES];   // [k][c], as given
    __shared__ float aggs[4][HIDDEN];
    const int tid = threadIdx.x;
    for (int i = tid; i < HIDDEN * N_CLASSES; i += 256) W2s[i] = W2[i];
    const int wave = tid >> 6, lane = tid & 63;
    const int node = blockIdx.x * 4 + wave;
    const int g = lane >> 3, sl = lane & 7;

    float acc[8];
#pragma unroll
    for (int j = 0; j < 8; ++j) acc[j] = 0.f;
    if (g == 0) {
        f16x8 v = *(const f16x8*)&A1[node * HIDDEN + sl * 8];
#pragma unroll
        for (int j = 0; j < 8; ++j) acc[j] = (float)v[j];
    }
    __syncthreads();   // W2s staged; placed before divergent-length gather

    const int beg = off[node], end = off[node + 1];
    for (int base = beg; base < end; base += 64) {
        int m = end - base; if (m > 64) m = 64;
        int vidx = (lane < m) ? (int)sorted[base + lane] : 0;
        int nfull = m & ~15;
        int i = 0;
        for (; i < nfull; i += 16) {
            int s0 = __shfl(vidx, i + g, 64);
            int s1 = __shfl(vidx, i + 8 + g, 64);
            f16x8 v0 = *(const f16x8*)&A1[s0 * HIDDEN + sl * 8];
            f16x8 v1 = *(const f16x8*)&A1[s1 * HIDDEN + sl * 8];
            f16x8 t = v0 + v1;
#pragma unroll
            for (int j = 0; j < 8; ++j)
                acc[j] += (float)t[j];
        }
        if (i < m) {
            int s0 = __shfl(vidx, i + g, 64);
            int s1 = __shfl(vidx, i + 8 + g, 64);
            f16x8 v0 = {};
            f16x8 v1 = {};
            if (i + g < m)     v0 = *(const f16x8*)&A1[s0 * HIDDEN + sl * 8];
            if (i + 8 + g < m) v1 = *(const f16x8*)&A1[s1 * HIDDEN + sl * 8];
            f16x8 t = v0 + v1;
#pragma unroll
            for (int j = 0; j < 8; ++j)
                acc[j] += (float)t[j];
        }
    }
#pragma unroll
    for (int j = 0; j < 8; ++j) {
        acc[j] += __shfl_xor(acc[j], 8, 64);
        acc[j] += __shfl_xor(acc[j], 16, 64);
        acc[j] += __shfl_xor(acc[j], 32, 64);
    }
    if (lane < 8) {
        f32x4 t0 = {acc[0], acc[1], acc[2], acc[3]};
        f32x4 t1 = {acc[4], acc[5], acc[6], acc[7]};
        *(f32x4*)&aggs[wave][lane * 8]     = t0;
        *(f32x4*)&aggs[wave][lane * 8 + 4] = t1;
    }
    __builtin_amdgcn_wave_barrier();   // same-wave LDS write->read ordering fence

    float z = -INFINITY;
    if (lane < N_CLASSES) {
        float s = 0.f;
        const float* ag = aggs[wave];
#pragma unroll
        for (int k = 0; k < HIDDEN; ++k)
            s = fmaf(ag[k], W2s[k * N_CLASSES + lane], s);
        z = fmaf(dinv[node], s, b2[lane]);
    }
    float mv = z;
#pragma unroll
    for (int d = 32; d > 0; d >>= 1) mv = fmaxf(mv, __shfl_xor(mv, d, 64));
    float ex = (lane < N_CLASSES) ? expf(z - mv) : 0.f;
#pragma unroll
    for (int d = 32; d > 0; d >>= 1) ex += __shfl_xor(ex, d, 64);
    float lse = mv + logf(ex);
    if (lane < N_CLASSES) out[node * N_CLASSES + lane] = z - lse;
}

// ---------------- launch ----------------

extern "C" void kernel_launch(void* const* d_in, const int* in_sizes, int n_in,
                              void* d_out, int out_size, void* d_ws, size_t ws_size,
                              hipStream_t stream) {
    const float* x  = (const float*)d_in[0];
    const int*   ei = (const int*)d_in[1];
    const float* W1 = (const float*)d_in[2];
    const float* b1 = (const float*)d_in[3];
    const float* W2 = (const float*)d_in[4];
    const float* b2 = (const float*)d_in[5];
    const int* row = ei;             // edge_index[0] = source
    const int* col = ei + N_EDGES;   // edge_index[1] = target

    char* ws = (char*)d_ws;
    int*            btot   = (int*)(ws + 0);             // 628 B
    int*            gcur   = (int*)(ws + 1024);          // 628 B
    int*            off    = (int*)(ws + 4096);          // 160 KB + 4
    float*          dinv   = (float*)(ws + 167936);      // 160 KB
    unsigned*       sedge  = (unsigned*)(ws + 335872);   // 5.12 MB (dead after bucketsort)
    unsigned short* sorted = (unsigned short*)(ws + 5455872); // 2.56 MB
    _Float16*       W1t    = (_Float16*)(ws + 8015872);  // 128 KB
    _Float16*       B1     = (_Float16*)(ws + 8146944);  // 5.12 MB : hs1 f16
    _Float16*       A1     = (_Float16*)(ws + 335872);   // 5.12 MB : reuse sedge slot

    hipMemsetAsync(btot, 0, 2048, stream);   // btot + gcur
    k_pre<<<HIST_BLOCKS + CONV_BLOCKS, 256, 0, stream>>>(col, btot, W1, W1t);
    k_binscatter<<<(N_EDGES + CHUNK - 1) / CHUNK, 256, 0, stream>>>(row, col, btot, gcur, sedge);
    k_bucketsort<<<NB, 256, 0, stream>>>(sedge, btot, off, dinv, sorted);

    k_gemm1<<<N_NODES / 64, 256, 0, stream>>>(x, W1t, dinv, B1);
    k_agg1<<<N_NODES / 4, 256, 0, stream>>>(off, sorted, B1, dinv, b1, A1);
    k_agg2_lsm<<<N_NODES / 4, 256, 0, stream>>>(off, sorted, A1, dinv, b2, W2, (float*)d_out);
}